// Round 1
// baseline (585.356 us; speedup 1.0000x reference)
//
#include <hip/hip_runtime.h>
#include <hip/hip_bf16.h>

typedef __bf16 bf16;
typedef __bf16 bf16x4 __attribute__((ext_vector_type(4)));
typedef __bf16 bf16x8 __attribute__((ext_vector_type(8)));
typedef float  f32x4  __attribute__((ext_vector_type(4)));

// Problem constants
static constexpr int NB   = 16;    // batch
static constexpr int NN   = 2048;  // nodes
static constexpr int HID  = 128;   // hidden / in_dim

// ---------------------------------------------------------------------------
// prep: W (128x128 fp32, [k][n]) -> WT bf16 [n][k], for all 3 layers
// ---------------------------------------------------------------------------
__global__ __launch_bounds__(256) void prep_wt(const float* __restrict__ W0,
                                               const float* __restrict__ W1,
                                               const float* __restrict__ W2,
                                               bf16* __restrict__ WT) {
    int l = blockIdx.x;
    const float* W = (l == 0) ? W0 : (l == 1) ? W1 : W2;
    bf16* out = WT + l * 128 * 128;
    int tid = threadIdx.x;
#pragma unroll
    for (int i = 0; i < 64; ++i) {
        int idx = i * 256 + tid;           // W row-major [k][n]
        int k = idx >> 7, n = idx & 127;
        out[n * 128 + k] = (bf16)W[idx];
    }
}

// ---------------------------------------------------------------------------
// small GEMM: tmp = h @ W, output TRANSPOSED as tmpT[b][n][k] (bf16)
//   A: (32768, 128) fp32 (layer0: x) or bf16 (h from previous layer)
//   B: WT (128,128) bf16 [n][k]
// Tile: BM=128, BN=128 (full), BK=64 (2 chunks). 256 thr = 4 waves.
// ---------------------------------------------------------------------------
template<typename TA>
__global__ __launch_bounds__(256) void small_gemm(const TA* __restrict__ A,
                                                  const bf16* __restrict__ WT,
                                                  bf16* __restrict__ tmpT) {
    __shared__ bf16 smem[2 * 128 * 72];
    bf16* As = smem;              // [128][72]
    bf16* Bs = smem + 128 * 72;   // [128][72]

    const int tid  = threadIdx.x;
    const int wave = tid >> 6, lane = tid & 63;
    const int c0 = lane & 15, q = lane >> 4;
    const int blk = blockIdx.x;
    const int row_g0 = blk * 128;   // flat row base in (32768,128)

    f32x4 acc[2][8] = {};

    for (int kk = 0; kk < 2; ++kk) {
        const int k0 = kk * 64;
        if constexpr (sizeof(TA) == 4) {
#pragma unroll
            for (int i = 0; i < 8; ++i) {
                int flat = i * 1024 + tid * 4;
                int row = flat >> 6, col = flat & 63;
                f32x4 v = *(const f32x4*)(A + (size_t)(row_g0 + row) * 128 + k0 + col);
                bf16x4 o = { (bf16)v.x, (bf16)v.y, (bf16)v.z, (bf16)v.w };
                *(bf16x4*)(As + row * 72 + col) = o;
            }
        } else {
#pragma unroll
            for (int i = 0; i < 4; ++i) {
                int flat = i * 2048 + tid * 8;
                int row = flat >> 6, col = flat & 63;
                bf16x8 v = *(const bf16x8*)((const bf16*)A + (size_t)(row_g0 + row) * 128 + k0 + col);
                *(bf16x8*)(As + row * 72 + col) = v;
            }
        }
#pragma unroll
        for (int i = 0; i < 4; ++i) {
            int flat = i * 2048 + tid * 8;
            int row = flat >> 6, col = flat & 63;
            bf16x8 v = *(const bf16x8*)(WT + (size_t)row * 128 + k0 + col);
            *(bf16x8*)(Bs + row * 72 + col) = v;
        }
        __syncthreads();
#pragma unroll
        for (int ks = 0; ks < 2; ++ks) {
            bf16x8 af[2];
#pragma unroll
            for (int mt = 0; mt < 2; ++mt)
                af[mt] = *(const bf16x8*)(As + (wave * 32 + mt * 16 + c0) * 72 + ks * 32 + q * 8);
#pragma unroll
            for (int nt = 0; nt < 8; ++nt) {
                bf16x8 bfr = *(const bf16x8*)(Bs + (nt * 16 + c0) * 72 + ks * 32 + q * 8);
#pragma unroll
                for (int mt = 0; mt < 2; ++mt)
                    acc[mt][nt] = __builtin_amdgcn_mfma_f32_16x16x32_bf16(af[mt], bfr, acc[mt][nt], 0, 0, 0);
            }
        }
        __syncthreads();
    }

    // Transposed write-out through LDS: Cs[n][m], row stride 136 (16B-aligned rows)
    bf16* Cs = smem;
#pragma unroll
    for (int mt = 0; mt < 2; ++mt) {
        int mbase = wave * 32 + mt * 16 + q * 4;
#pragma unroll
        for (int nt = 0; nt < 8; ++nt) {
            int n = nt * 16 + c0;
#pragma unroll
            for (int r = 0; r < 4; ++r)
                Cs[n * 136 + mbase + r] = (bf16)acc[mt][nt][r];
        }
    }
    __syncthreads();
    const int b    = blk >> 4;          // 16 blocks per batch (2048/128)
    const int row0 = (blk & 15) * 128;
    bf16* outp = tmpT + (size_t)b * 128 * 2048;
#pragma unroll
    for (int i = 0; i < 8; ++i) {
        int flat = i * 2048 + tid * 8;
        int n = flat >> 7, m = flat & 127;
        bf16x8 v = *(const bf16x8*)(Cs + n * 136 + m);
        *(bf16x8*)(outp + (size_t)n * 2048 + row0 + m) = v;
    }
}

// ---------------------------------------------------------------------------
// big GEMM + fused bias/LayerNorm/ReLU epilogue
//   C[b] (2048x128) = adj[b](2048x2048) @ tmp[b](2048x128)
//   AMODE: 0 = read adj fp32; 1 = read adj fp32 + write adjB bf16; 2 = read adjB
// Tile: BM=128, BN=128 (full), BK=64, 32 K-iters. 256 thr = 4 waves.
// ---------------------------------------------------------------------------
template<int AMODE, bool OUTF32>
__global__ __launch_bounds__(256) void big_gemm(const float* __restrict__ Af,
                                                bf16* __restrict__ adjB,
                                                const bf16* __restrict__ Bt,   // tmpT (16,128,2048)
                                                const float* __restrict__ bias,
                                                const float* __restrict__ gamma,
                                                const float* __restrict__ betap,
                                                bf16* __restrict__ outB,
                                                float* __restrict__ outF) {
    __shared__ bf16 As[128 * 72];
    __shared__ bf16 Bs[128 * 72];

    const int tid  = threadIdx.x;
    const int wave = tid >> 6, lane = tid & 63;
    const int c0 = lane & 15, q = lane >> 4;
    const int b  = blockIdx.z;
    const int m0 = blockIdx.x * 128;
    const size_t abase = (size_t)b * 2048 * 2048;
    const bf16* Btb = Bt + (size_t)b * 128 * 2048;

    f32x4 acc[2][8] = {};

    for (int kk = 0; kk < 32; ++kk) {
        const int k0 = kk * 64;
        if constexpr (AMODE <= 1) {
#pragma unroll
            for (int i = 0; i < 8; ++i) {
                int flat = i * 1024 + tid * 4;
                int row = flat >> 6, col = flat & 63;
                f32x4 v = *(const f32x4*)(Af + abase + (size_t)(m0 + row) * 2048 + k0 + col);
                bf16x4 o = { (bf16)v.x, (bf16)v.y, (bf16)v.z, (bf16)v.w };
                *(bf16x4*)(As + row * 72 + col) = o;
                if constexpr (AMODE == 1)
                    *(bf16x4*)(adjB + abase + (size_t)(m0 + row) * 2048 + k0 + col) = o;
            }
        } else {
#pragma unroll
            for (int i = 0; i < 4; ++i) {
                int flat = i * 2048 + tid * 8;
                int row = flat >> 6, col = flat & 63;
                bf16x8 v = *(const bf16x8*)(adjB + abase + (size_t)(m0 + row) * 2048 + k0 + col);
                *(bf16x8*)(As + row * 72 + col) = v;
            }
        }
#pragma unroll
        for (int i = 0; i < 4; ++i) {
            int flat = i * 2048 + tid * 8;
            int row = flat >> 6, col = flat & 63;
            bf16x8 v = *(const bf16x8*)(Btb + (size_t)row * 2048 + k0 + col);
            *(bf16x8*)(Bs + row * 72 + col) = v;
        }
        __syncthreads();
#pragma unroll
        for (int ks = 0; ks < 2; ++ks) {
            bf16x8 af[2];
#pragma unroll
            for (int mt = 0; mt < 2; ++mt)
                af[mt] = *(const bf16x8*)(As + (wave * 32 + mt * 16 + c0) * 72 + ks * 32 + q * 8);
#pragma unroll
            for (int nt = 0; nt < 8; ++nt) {
                bf16x8 bfr = *(const bf16x8*)(Bs + (nt * 16 + c0) * 72 + ks * 32 + q * 8);
#pragma unroll
                for (int mt = 0; mt < 2; ++mt)
                    acc[mt][nt] = __builtin_amdgcn_mfma_f32_16x16x32_bf16(af[mt], bfr, acc[mt][nt], 0, 0, 0);
            }
        }
        __syncthreads();
    }

    // ---- epilogue: + bias, LayerNorm over n (128), *g + beta, ReLU ----
    float bv[8], gv[8], bev[8];
#pragma unroll
    for (int nt = 0; nt < 8; ++nt) {
        int n = nt * 16 + c0;
        bv[nt] = bias[n]; gv[nt] = gamma[n]; bev[nt] = betap[n];
    }
#pragma unroll
    for (int mt = 0; mt < 2; ++mt) {
#pragma unroll
        for (int r = 0; r < 4; ++r) {
            float s1 = 0.f, s2 = 0.f;
            float v[8];
#pragma unroll
            for (int nt = 0; nt < 8; ++nt) {
                float x = acc[mt][nt][r] + bv[nt];
                v[nt] = x; s1 += x; s2 += x * x;
            }
            // row m lives in lanes [q*16, q*16+16): reduce over the 16-lane group
#pragma unroll
            for (int off = 1; off < 16; off <<= 1) {
                s1 += __shfl_xor(s1, off);
                s2 += __shfl_xor(s2, off);
            }
            float mu  = s1 * (1.f / 128.f);
            float var = s2 * (1.f / 128.f) - mu * mu;
            float rs  = rsqrtf(var + 1e-5f);
            int m = m0 + wave * 32 + mt * 16 + q * 4 + r;
            size_t rowoff = ((size_t)b * 2048 + m) * 128;
#pragma unroll
            for (int nt = 0; nt < 8; ++nt) {
                int n = nt * 16 + c0;
                float o = (v[nt] - mu) * rs * gv[nt] + bev[nt];
                o = fmaxf(o, 0.f);
                if constexpr (OUTF32) outF[rowoff + n] = o;
                else                  outB[rowoff + n] = (bf16)o;
            }
        }
    }
}

// ---------------------------------------------------------------------------
extern "C" void kernel_launch(void* const* d_in, const int* in_sizes, int n_in,
                              void* d_out, int out_size, void* d_ws, size_t ws_size,
                              hipStream_t stream) {
    const float* x   = (const float*)d_in[0];
    const float* adj = (const float*)d_in[1];
    const float* W[3]  = {(const float*)d_in[2],  (const float*)d_in[6],  (const float*)d_in[10]};
    const float* bb[3] = {(const float*)d_in[3],  (const float*)d_in[7],  (const float*)d_in[11]};
    const float* gg[3] = {(const float*)d_in[4],  (const float*)d_in[8],  (const float*)d_in[12]};
    const float* be[3] = {(const float*)d_in[5],  (const float*)d_in[9],  (const float*)d_in[13]};

    char* ws = (char*)d_ws;
    size_t off = 0;
    bf16* WT   = (bf16*)(ws + off); off += (size_t)3 * 128 * 128 * 2;
    off = (off + 255) & ~(size_t)255;
    bf16* tmpT = (bf16*)(ws + off); off += (size_t)NB * 128 * NN * 2;   // 8 MiB
    bf16* hB   = (bf16*)(ws + off); off += (size_t)NB * NN * 128 * 2;   // 8 MiB
    bf16* adjB = (bf16*)(ws + off); off += (size_t)NB * NN * NN * 2;    // 128 MiB
    const bool use_adjB = (ws_size >= off);

    float* outF = (float*)d_out;

    prep_wt<<<3, 256, 0, stream>>>(W[0], W[1], W[2], WT);

    dim3 bg(16, 1, 16);
    // ---- layer 0 ----
    small_gemm<float><<<256, 256, 0, stream>>>(x, WT, tmpT);
    if (use_adjB)
        big_gemm<1, false><<<bg, 256, 0, stream>>>(adj, adjB, tmpT, bb[0], gg[0], be[0], hB, nullptr);
    else
        big_gemm<0, false><<<bg, 256, 0, stream>>>(adj, adjB, tmpT, bb[0], gg[0], be[0], hB, nullptr);
    // ---- layer 1 ----
    small_gemm<bf16><<<256, 256, 0, stream>>>(hB, WT + 128 * 128, tmpT);
    if (use_adjB)
        big_gemm<2, false><<<bg, 256, 0, stream>>>(adj, adjB, tmpT, bb[1], gg[1], be[1], hB, nullptr);
    else
        big_gemm<0, false><<<bg, 256, 0, stream>>>(adj, adjB, tmpT, bb[1], gg[1], be[1], hB, nullptr);
    // ---- layer 2 ----
    small_gemm<bf16><<<256, 256, 0, stream>>>(hB, WT + 2 * 128 * 128, tmpT);
    if (use_adjB)
        big_gemm<2, true><<<bg, 256, 0, stream>>>(adj, adjB, tmpT, bb[2], gg[2], be[2], nullptr, outF);
    else
        big_gemm<0, true><<<bg, 256, 0, stream>>>(adj, adjB, tmpT, bb[2], gg[2], be[2], nullptr, outF);
}